// Round 8
// baseline (260.072 us; speedup 1.0000x reference)
//
#include <hip/hip_runtime.h>

// MultiheadAttention: B=2, L=4096, D=512, H=8, HD=64. fp32 I/O, bf16 MFMA inside.
// prep -> QKV GEMM (scatter [B,H,L,HD], Q pre-scaled by 0.125*log2e) ->
// V^T [BH,HD,L] -> flash attention split-K=2 (transposed S^T/O^T, fixed-max
// softmax, l via ones-MFMA, K dbuf via global_load_lds DMA + XOR swizzle,
// V direct from global/L2) -> merge (O1+O2)/(l1+l2) -> out GEMM (fp32).

#define B_  2
#define L_  4096
#define D_  512
#define H_  8
#define HD_ 64
#define BH_ (B_*H_)               // 16
#define M_  (B_*L_)               // 8192
#define QKVN (3*D_)               // 1536
#define HEADSZ (BH_*L_*HD_)       // 4194304 elems per Q/K/V buffer

typedef unsigned short ushort;
typedef unsigned int uint;
typedef __bf16 bf16x8 __attribute__((ext_vector_type(8)));
typedef __bf16 bf16x2 __attribute__((ext_vector_type(2)));
typedef float  f32x4  __attribute__((ext_vector_type(4)));

typedef const __attribute__((address_space(1))) void g_void;
typedef __attribute__((address_space(3))) void l_void;

__device__ __forceinline__ ushort f2bf(float f) {
    __bf16 h = (__bf16)f;           // RNE
    return __builtin_bit_cast(ushort, h);
}
__device__ __forceinline__ float bf2f(ushort u) {
    uint x = ((uint)u) << 16;
    return __builtin_bit_cast(float, x);
}
__device__ __forceinline__ uint pk_bf16(float a, float b) {
#if __has_builtin(__builtin_amdgcn_cvt_pk_bf16_f32)
    bf16x2 v = __builtin_amdgcn_cvt_pk_bf16_f32(a, b);
    return __builtin_bit_cast(uint, v);
#else
    return (uint)f2bf(a) | ((uint)f2bf(b) << 16);
#endif
}

// ---- fused prep: cvt x (fp32->bf16) + transpose+cvt both weight matrices ----
__global__ __launch_bounds__(256)
void prep_k(const float* __restrict__ x, ushort* __restrict__ xb,
            const float* __restrict__ wq, ushort* __restrict__ wtq,
            const float* __restrict__ wo, ushort* __restrict__ wto)
{
    int bid = blockIdx.x, tid = threadIdx.x;
    if (bid < 4096) {
        int idx = bid * 256 + tid;
        float4 v = ((const float4*)x)[idx];
        ushort4 o; o.x = f2bf(v.x); o.y = f2bf(v.y); o.z = f2bf(v.z); o.w = f2bf(v.w);
        ((ushort4*)xb)[idx] = o;
    } else if (bid < 7168) {
        int idx = (bid - 4096) * 256 + tid;
        int c = idx / D_, r = idx % D_;
        wtq[idx] = f2bf(wq[r * QKVN + c]);
    } else {
        int idx = (bid - 7168) * 256 + tid;
        int c = idx / D_, r = idx % D_;
        wto[idx] = f2bf(wo[r * D_ + c]);
    }
}

// -------- bf16 V [BH][L][64] -> VT [BH][64][L], LDS-tiled --------
#define TP 66
__global__ __launch_bounds__(256)
void transpose_v(const ushort* __restrict__ V, ushort* __restrict__ VT) {
    __shared__ ushort T[64 * TP];
    const int tid = threadIdx.x;
    const int bh = blockIdx.y;
    const int l0 = blockIdx.x * 64;
    const int base = bh * (L_ * HD_);
    #pragma unroll
    for (int i = 0; i < 2; i++) {
        int c = i * 256 + tid;
        int l = c >> 3, dc = (c & 7) * 8;
        uint4 v = *(const uint4*)&V[base + (l0 + l) * HD_ + dc];
        uint* p = (uint*)&T[l * TP + dc];
        p[0] = v.x; p[1] = v.y; p[2] = v.z; p[3] = v.w;
    }
    __syncthreads();
    #pragma unroll
    for (int p = 0; p < 2; p++) {
        int c = p * 256 + tid;
        int d = c >> 3, lb = c & 7;
        ushort tmp[8];
        #pragma unroll
        for (int j = 0; j < 8; j++) tmp[j] = T[(lb * 8 + j) * TP + d];
        *(uint4*)&VT[base + d * L_ + l0 + lb * 8] = *(uint4*)tmp;
    }
}

// ---------------- GEMM: C[M,N] = A[M,K] @ Bt[N,K]^T + bias ----------------
// mode 0: fp32 store [M,N]
// mode 1: QKV scatter -> Q|K|V each [B,H,L,HD] bf16; Q scaled by 0.125*log2e
__global__ __launch_bounds__(256)
void gemm_bt(const ushort* __restrict__ A, const ushort* __restrict__ Bt,
             const float* __restrict__ bias, void* __restrict__ out,
             int M, int N, int K, int mode)
{
    __shared__ ushort As[128 * 32];
    __shared__ ushort Bs[128 * 32];

    const int tid  = threadIdx.x;
    const int lane = tid & 63;
    const int wid  = tid >> 6;
    const int wm   = wid >> 1, wn = wid & 1;
    const int lr   = lane & 15;
    const int quad = lane >> 4;
    const int tm = blockIdx.x, tn = blockIdx.y;

    f32x4 acc[4][4] = {};
    const int arow = tm * 128;
    const int brow = tn * 128;

    for (int k0 = 0; k0 < K; k0 += 32) {
        #pragma unroll
        for (int i = 0; i < 2; i++) {
            int c   = i * 256 + tid;
            int row = c >> 2;
            int kk  = (c & 3) * 8;
            __builtin_amdgcn_global_load_lds(
                (g_void*)&A[(size_t)(arow + row) * K + k0 + kk],
                (l_void*)&As[c * 8], 16, 0, 0);
            __builtin_amdgcn_global_load_lds(
                (g_void*)&Bt[(size_t)(brow + row) * K + k0 + kk],
                (l_void*)&Bs[c * 8], 16, 0, 0);
        }
        __syncthreads();

        bf16x8 af[4], bfr[4];
        #pragma unroll
        for (int t = 0; t < 4; t++) {
            af [t] = *(const bf16x8*)&As[(wm * 64 + t * 16 + lr) * 32 + quad * 8];
            bfr[t] = *(const bf16x8*)&Bs[(wn * 64 + t * 16 + lr) * 32 + quad * 8];
        }
        #pragma unroll
        for (int mt = 0; mt < 4; mt++)
            #pragma unroll
            for (int nt = 0; nt < 4; nt++)
                acc[mt][nt] = __builtin_amdgcn_mfma_f32_16x16x32_bf16(
                    af[mt], bfr[nt], acc[mt][nt], 0, 0, 0);
        __syncthreads();
    }

    const float QSCALE = 0.18033688011112042f;   // 0.125 * log2(e)
    #pragma unroll
    for (int nt = 0; nt < 4; nt++) {
        int col = tn * 128 + wn * 64 + nt * 16 + lr;
        float bv = bias[col];
        #pragma unroll
        for (int mt = 0; mt < 4; mt++) {
            #pragma unroll
            for (int r = 0; r < 4; r++) {
                int row = tm * 128 + wm * 64 + mt * 16 + quad * 4 + r;
                float v = acc[mt][nt][r] + bv;
                if (mode == 0) {
                    ((float*)out)[(size_t)row * N + col] = v;
                } else {
                    int d = col & 63;
                    int g = col >> 6;
                    int which = g % 3;
                    int h = g / 3;
                    int b = row >> 12;
                    int l = row & (L_ - 1);
                    if (which == 0) v *= QSCALE;
                    ((ushort*)out)[which * HEADSZ + (((b * H_ + h) * L_ + l) * HD_) + d]
                        = f2bf(v);
                }
            }
        }
    }
}

// ---------------- flash attention, split-K=2 ----------------
// grid (L/128, BH, 2): z = key-half. 256 thr = 4 waves, wave owns 32 q-rows.
// K tile [key][d] dbuf in unpadded LDS via global_load_lds w=16 + XOR-swizzled
// source chunks; V^T frags read DIRECT from global (L2-resident, issued right
// after the barrier, consumed ~400 cyc later). Fixed-max softmax (p=exp2(s),
// scale folded into Q); l via ones-MFMA. Outputs UNNORMALIZED bf16 partial
// [M,D] + fp32 l partial; merge_k normalizes.
#define PP 72
__global__ __launch_bounds__(256, 4)
void attn_k(const ushort* __restrict__ Q, const ushort* __restrict__ K,
            const ushort* __restrict__ VT, ushort* __restrict__ Opart,
            float* __restrict__ lpart)
{
    __shared__ ushort Ks[2][64 * 64];
    __shared__ ushort Pw[4][32 * PP];

    const int tid  = threadIdx.x;
    const int lane = tid & 63;
    const int wid  = tid >> 6;          // 0..3
    const int lr   = lane & 15;
    const int quad = lane >> 4;
    const int bh   = blockIdx.y;
    const int q0   = blockIdx.x * 128;
    const int half = blockIdx.z;
    const int base = bh * (L_ * HD_);
    const int t0   = half * 32;          // 32 tiles of 64 keys = 2048 keys

    const int srow = wid * 8 + (lane >> 3);
    const int sc8  = lane & 7;

    bf16x8 qf[2][2];
    #pragma unroll
    for (int mt = 0; mt < 2; mt++) {
        int qrow = q0 + wid * 32 + mt * 16 + lr;
        qf[mt][0] = *(const bf16x8*)&Q[base + qrow * HD_ +      quad * 8];
        qf[mt][1] = *(const bf16x8*)&Q[base + qrow * HD_ + 32 + quad * 8];
    }

    bf16x8 onef;
    #pragma unroll
    for (int j = 0; j < 8; j++) onef[j] = (__bf16)1.0f;

    f32x4 o_acc[2][4] = {};
    f32x4 l_acc[2] = {};

    // prologue: DMA K tile t0 into buffer 0
    #pragma unroll
    for (int i = 0; i < 2; i++) {
        int row = i * 32 + srow;
        int cs = ((sc8 ^ (row & 7))) * 8;
        __builtin_amdgcn_global_load_lds(
            (g_void*)&K[base + (t0 * 64 + row) * HD_ + cs],
            (l_void*)&Ks[0][(i * 32 + wid * 8) * 64 + lane * 8], 16, 0, 0);
    }

    for (int t = t0; t < t0 + 32; t++) {
        const int cur = (t - t0) & 1;
        const int s0 = t * 64;
        __syncthreads();

        // DMA K tile t+1 — in flight during compute(t)
        if (t + 1 < t0 + 32) {
            #pragma unroll
            for (int i = 0; i < 2; i++) {
                int row = i * 32 + srow;
                int cs = ((sc8 ^ (row & 7))) * 8;
                __builtin_amdgcn_global_load_lds(
                    (g_void*)&K[base + (s0 + 64 + row) * HD_ + cs],
                    (l_void*)&Ks[cur ^ 1][(i * 32 + wid * 8) * 64 + lane * 8], 16, 0, 0);
            }
        }

        // V^T frags direct from global (L2); issued early, consumed after softmax
        bf16x8 vf[2][4];
        #pragma unroll
        for (int ks = 0; ks < 2; ks++)
            #pragma unroll
            for (int nt = 0; nt < 4; nt++)
                vf[ks][nt] = *(const bf16x8*)&VT[base + (nt * 16 + lr) * L_
                                                 + s0 + ks * 32 + quad * 8];

        // S^T = K · Q^T
        f32x4 sc[2][4] = {};
        #pragma unroll
        for (int kk = 0; kk < 2; kk++) {
            #pragma unroll
            for (int nt = 0; nt < 4; nt++) {
                int row = nt * 16 + lr;
                bf16x8 kf = *(const bf16x8*)
                    &Ks[cur][row * 64 + (((kk * 4 + quad) ^ (row & 7)) * 8)];
                #pragma unroll
                for (int mt = 0; mt < 2; mt++)
                    sc[mt][nt] = __builtin_amdgcn_mfma_f32_16x16x32_bf16(
                        kf, qf[mt][kk], sc[mt][nt], 0, 0, 0);
            }
        }

        // p = exp2(s); packed bf16; P^T b64 into Pw
        #pragma unroll
        for (int mt = 0; mt < 2; mt++) {
            #pragma unroll
            for (int nt = 0; nt < 4; nt++) {
                uint2 p2;
                p2.x = pk_bf16(exp2f(sc[mt][nt][0]), exp2f(sc[mt][nt][1]));
                p2.y = pk_bf16(exp2f(sc[mt][nt][2]), exp2f(sc[mt][nt][3]));
                *(uint2*)&Pw[wid][(mt * 16 + lr) * PP + nt * 16 + quad * 4] = p2;
            }
        }
        // Pw same-wave RAW: compiler inserts lgkmcnt wait; no barrier needed

        // O^T += V^T·P^T ; l_acc += ones·P^T (col sums = l per query)
        #pragma unroll
        for (int ks = 0; ks < 2; ks++) {
            bf16x8 pfr[2];
            #pragma unroll
            for (int mt = 0; mt < 2; mt++)
                pfr[mt] = *(const bf16x8*)
                    &Pw[wid][(mt * 16 + lr) * PP + ks * 32 + quad * 8];
            #pragma unroll
            for (int nt = 0; nt < 4; nt++)
                #pragma unroll
                for (int mt = 0; mt < 2; mt++)
                    o_acc[mt][nt] = __builtin_amdgcn_mfma_f32_16x16x32_bf16(
                        vf[ks][nt], pfr[mt], o_acc[mt][nt], 0, 0, 0);
            #pragma unroll
            for (int mt = 0; mt < 2; mt++)
                l_acc[mt] = __builtin_amdgcn_mfma_f32_16x16x32_bf16(
                    onef, pfr[mt], l_acc[mt], 0, 0, 0);
        }
    }

    // l partial (all 16 regs/lanes of a column identical; quad 0 writes)
    if (quad == 0) {
        #pragma unroll
        for (int mt = 0; mt < 2; mt++)
            lpart[(half * BH_ + bh) * L_ + q0 + wid * 32 + mt * 16 + lr]
                = l_acc[mt][0];
    }

    // epilogue: unnormalized O^T -> transpose via per-wave Pw -> bf16 [M,D]
    #pragma unroll
    for (int mt = 0; mt < 2; mt++) {
        #pragma unroll
        for (int nt = 0; nt < 4; nt++) {
            uint2 p2;
            p2.x = pk_bf16(o_acc[mt][nt][0], o_acc[mt][nt][1]);
            p2.y = pk_bf16(o_acc[mt][nt][2], o_acc[mt][nt][3]);
            *(uint2*)&Pw[wid][(mt * 16 + lr) * PP + nt * 16 + quad * 4] = p2;
        }
    }
    const int b = bh >> 3, h = bh & 7;
    ushort* Oh = Opart + (size_t)half * M_ * D_;
    #pragma unroll
    for (int i = 0; i < 4; i++) {
        int c = i * 64 + lane;
        int row = c >> 3, dc = (c & 7) * 8;
        ushort tmp[8];
        #pragma unroll
        for (int j = 0; j < 8; j++) tmp[j] = Pw[wid][row * PP + dc + j];
        *(uint4*)&Oh[((size_t)(b * L_ + q0 + wid * 32 + row)) * D_ + h * HD_ + dc]
            = *(uint4*)tmp;
    }
}

// ---------------- merge: attn = (O1 + O2) / (l1 + l2), bf16 ----------------
__global__ __launch_bounds__(256)
void merge_k(const ushort* __restrict__ Op, const float* __restrict__ lp,
             ushort* __restrict__ attn)
{
    int idx = blockIdx.x * 256 + threadIdx.x;      // ushort4 chunk, M*D/4 total
    int row = idx >> 7;                            // D/4 = 128 chunks per row
    int c4  = (idx & 127) * 4;
    int h = c4 >> 6;
    int b = row >> 12, l = row & (L_ - 1);
    int bh = b * H_ + h;
    float inv = 1.0f / (lp[bh * L_ + l] + lp[(BH_ + bh) * L_ + l]);
    ushort4 a = *(const ushort4*)&Op[(size_t)row * D_ + c4];
    ushort4 c = *(const ushort4*)&Op[(size_t)(M_ + row) * D_ + c4];
    ushort4 o;
    o.x = f2bf((bf2f(a.x) + bf2f(c.x)) * inv);
    o.y = f2bf((bf2f(a.y) + bf2f(c.y)) * inv);
    o.z = f2bf((bf2f(a.z) + bf2f(c.z)) * inv);
    o.w = f2bf((bf2f(a.w) + bf2f(c.w)) * inv);
    *(ushort4*)&attn[(size_t)row * D_ + c4] = o;
}

extern "C" void kernel_launch(void* const* d_in, const int* in_sizes, int n_in,
                              void* d_out, int out_size, void* d_ws, size_t ws_size,
                              hipStream_t stream)
{
    const float* x     = (const float*)d_in[0];
    const float* w_qkv = (const float*)d_in[1];
    const float* b_qkv = (const float*)d_in[2];
    const float* w_o   = (const float*)d_in[3];
    const float* b_o   = (const float*)d_in[4];

    char* ws = (char*)d_ws;
    size_t o = 0;
    ushort* xb    = (ushort*)(ws + o); o += (size_t)M_ * D_ * 2;       // 8 MB (reused as VT)
    ushort* qkv   = (ushort*)(ws + o); o += (size_t)3 * HEADSZ * 2;    // 24 MB
    ushort* attn  = (ushort*)(ws + o); o += (size_t)M_ * D_ * 2;       // 8 MB
    ushort* opart = (ushort*)(ws + o); o += (size_t)2 * M_ * D_ * 2;   // 16 MB
    float*  lpart = (float*)(ws + o);  o += (size_t)2 * BH_ * L_ * 4;  // 0.5 MB
    ushort* wtq   = (ushort*)(ws + o); o += (size_t)QKVN * D_ * 2;     // 1.5 MB
    ushort* wto   = (ushort*)(ws + o);                                 // 0.5 MB
    ushort* vt    = xb;   // xb dead after QKV GEMM

    hipLaunchKernelGGL(prep_k, dim3(8192), dim3(256), 0, stream,
                       x, xb, w_qkv, wtq, w_o, wto);
    hipLaunchKernelGGL(gemm_bt, dim3(M_ / 128, QKVN / 128), dim3(256), 0, stream,
                       xb, wtq, b_qkv, (void*)qkv, M_, QKVN, D_, 1);
    hipLaunchKernelGGL(transpose_v, dim3(L_ / 64, BH_), dim3(256), 0, stream,
                       qkv + 2 * HEADSZ, vt);
    hipLaunchKernelGGL(attn_k, dim3(L_ / 128, BH_, 2), dim3(256), 0, stream,
                       qkv, qkv + HEADSZ, vt, opart, lpart);
    hipLaunchKernelGGL(merge_k, dim3(M_ * D_ / 4 / 256), dim3(256), 0, stream,
                       opart, lpart, attn);
    hipLaunchKernelGGL(gemm_bt, dim3(M_ / 128, D_ / 128), dim3(256), 0, stream,
                       attn, wto, b_o, d_out, M_, D_, D_, 0);
}